// Round 1
// baseline (67.210 us; speedup 1.0000x reference)
//
#include <hip/hip_runtime.h>

#define HD 32

// One wave (64 threads) per block; lanes [0..31] = batch 2*bid, lanes [32..63] = batch 2*bid+1.
// Lane (half, j) owns hidden unit j of its batch: holds W_ih row j and W_hh row j in VGPRs.
// h and x_t are broadcast within each half-wave through a tiny double-buffered LDS tile.
__global__ __launch_bounds__(64, 2)
void rnn_fused(const float* __restrict__ x,
               const float* __restrict__ h0,
               const float* __restrict__ W_ih,
               const float* __restrict__ W_hh,
               const float* __restrict__ b_ih,
               const float* __restrict__ b_hh,
               const float* __restrict__ W_out,
               const float* __restrict__ b_out,
               float* __restrict__ out,
               int B, int T)
{
    __shared__ __align__(16) float hs[2][2][HD];   // [buf][half][j]
    __shared__ __align__(16) float xs[2][2][HD];

    const int l = threadIdx.x;
    const int half = l >> 5;
    const int j = l & 31;
    const int b = blockIdx.x * 2 + half;

    // Per-lane weight rows (lane j of each half loads row j; duplicated loads hit cache).
    float wih[HD], whh[HD];
    {
        const float4* wr = reinterpret_cast<const float4*>(W_ih + j * HD);
        const float4* hr = reinterpret_cast<const float4*>(W_hh + j * HD);
#pragma unroll
        for (int c = 0; c < HD / 4; ++c) {
            float4 a = wr[c];
            wih[4*c+0] = a.x; wih[4*c+1] = a.y; wih[4*c+2] = a.z; wih[4*c+3] = a.w;
            float4 e = hr[c];
            whh[4*c+0] = e.x; whh[4*c+1] = e.y; whh[4*c+2] = e.z; whh[4*c+3] = e.w;
        }
    }

    const float bias = b_ih[j] + b_hh[j];
    float hval = h0[b * HD + j];

    const float* xb = x + (size_t)b * T * HD + j;
    float xv = xb[0];                  // x[b, 0, j]
    int buf = 0;

#pragma unroll 2
    for (int t = 0; t < T; ++t) {
        // Prefetch next timestep's x element (1-step lookahead hides HBM latency).
        float xnext = 0.0f;
        if (t + 1 < T) xnext = xb[(size_t)(t + 1) * HD];

        hs[buf][half][j] = hval;
        xs[buf][half][j] = xv;
        __syncthreads();               // single wave: acts as a compiler/LDS fence

        float acc = bias;
        const float4* hv = reinterpret_cast<const float4*>(hs[buf][half]);
        const float4* xw = reinterpret_cast<const float4*>(xs[buf][half]);
#pragma unroll
        for (int c = 0; c < HD / 4; ++c) {
            float4 h4 = hv[c];
            float4 x4 = xw[c];
            acc = fmaf(h4.x, whh[4*c+0], acc);
            acc = fmaf(h4.y, whh[4*c+1], acc);
            acc = fmaf(h4.z, whh[4*c+2], acc);
            acc = fmaf(h4.w, whh[4*c+3], acc);
            acc = fmaf(x4.x, wih[4*c+0], acc);
            acc = fmaf(x4.y, wih[4*c+1], acc);
            acc = fmaf(x4.z, wih[4*c+2], acc);
            acc = fmaf(x4.w, wih[4*c+3], acc);
        }
        hval = fmaxf(acc, 0.0f);
        xv = xnext;
        buf ^= 1;
    }

    // Outputs: d_out = [pred (B floats), hT (B*HD floats)]
    out[B + b * HD + j] = hval;

    float p = hval * W_out[j];
#pragma unroll
    for (int off = 16; off >= 1; off >>= 1)
        p += __shfl_xor(p, off, 64);   // reduces within each 32-lane half
    if (j == 0) out[b] = p + b_out[0];
}

extern "C" void kernel_launch(void* const* d_in, const int* in_sizes, int n_in,
                              void* d_out, int out_size, void* d_ws, size_t ws_size,
                              hipStream_t stream) {
    const float* x      = (const float*)d_in[0];
    const float* hidden = (const float*)d_in[1];
    const float* W_ih   = (const float*)d_in[2];
    const float* W_hh   = (const float*)d_in[3];
    const float* b_ih   = (const float*)d_in[4];
    const float* b_hh   = (const float*)d_in[5];
    const float* W_out  = (const float*)d_in[6];
    const float* b_out  = (const float*)d_in[7];
    float* out = (float*)d_out;

    const int B = in_sizes[1] / HD;            // hidden is (1, B, H)
    const int T = in_sizes[0] / (B * HD);      // x is (B, T, IN), IN == HD == 32

    rnn_fused<<<dim3(B / 2), dim3(64), 0, stream>>>(
        x, hidden, W_ih, W_hh, b_ih, b_hh, W_out, b_out, out, B, T);
}

// Round 2
// 48.170 us; speedup vs baseline: 1.3953x; 1.3953x over previous
//
#include <hip/hip_runtime.h>

#define HD 32
#define CH 8

typedef __attribute__((ext_vector_type(8))) short bf16x8;
typedef __attribute__((ext_vector_type(4))) float f32x4;

__device__ __forceinline__ int cvtpk_bf16(float a, float b) {
    int r;
    asm("v_cvt_pk_bf16_f32 %0, %1, %2" : "=v"(r) : "v"(a), "v"(b));
    return r;  // packed [bf16(b) | bf16(a)], a in low 16
}

// f32 pair -> bf16 hi dword + bf16 residual (lo) dword
__device__ __forceinline__ void split_pair(float a, float b, int& hi, int& lo) {
    hi = cvtpk_bf16(a, b);
    float fa = __int_as_float(hi << 16);
    float fb = __int_as_float((unsigned)hi & 0xffff0000u);
    lo = cvtpk_bf16(a - fa, b - fb);
}

__device__ __forceinline__ bf16x8 pack4(int w0, int w1, int w2, int w3) {
    union { int i[4]; bf16x8 v; } u;
    u.i[0] = w0; u.i[1] = w1; u.i[2] = w2; u.i[3] = w3;
    return u.v;
}

// 8 consecutive f32 (two float4) -> split bf16 A/B fragment (hi, lo)
__device__ __forceinline__ void split_frag(f32x4 a, f32x4 b, bf16x8& hi, bf16x8& lo) {
    int h0,h1,h2,h3,l0,l1,l2,l3;
    split_pair(a[0], a[1], h0, l0);
    split_pair(a[2], a[3], h1, l1);
    split_pair(b[0], b[1], h2, l2);
    split_pair(b[2], b[3], h3, l3);
    hi = pack4(h0,h1,h2,h3);
    lo = pack4(l0,l1,l2,l3);
}

#define MFMA(a,b,c) __builtin_amdgcn_mfma_f32_16x16x32_bf16((a),(b),(c),0,0,0)
#define BPERM(addr,v) __builtin_amdgcn_ds_bpermute((addr),(v))

// Block = 16 batches. Wave 0 = producer (x projection), wave 1 = consumer (recurrence).
// MFMA 16x16x32: A lane: row m=l&15, k=(l>>4)*8+e;  B lane: col n=l&15, k=(l>>4)*8+e;
// C/D lane: col n=l&15, rows (l>>4)*4+r (verified layout, learn_hip m89).
__global__ __launch_bounds__(128)
void rnn_mfma(const float* __restrict__ x,
              const float* __restrict__ h0p,
              const float* __restrict__ W_ih,
              const float* __restrict__ W_hh,
              const float* __restrict__ b_ih,
              const float* __restrict__ b_hh,
              const float* __restrict__ W_out,
              const float* __restrict__ b_out,
              float* __restrict__ out,
              int B, int T)
{
    __shared__ f32x4 xp_lds[2][CH][2][64];   // [buf][t_in_chunk][j-half][lane], 32 KB

    const int tid = threadIdx.x;
    const int wid = tid >> 6;
    const int l   = tid & 63;
    const int q   = l >> 4;          // quad
    const int c   = l & 15;          // col / batch-in-block / A-row
    const int bglob = blockIdx.x * 16 + c;
    const int nch = T / CH;

    // producer state
    bf16x8 pA_h0 = {}, pA_l0 = {}, pA_h1 = {}, pA_l1 = {};
    f32x4 bias0 = {0,0,0,0}, bias1 = {0,0,0,0};
    // consumer state
    bf16x8 cA_h0 = {}, cA_l0 = {}, cA_h1 = {}, cA_l1 = {};
    bf16x8 h_hi = {}, h_lo = {};
    f32x4 wo0 = {0,0,0,0}, wo1 = {0,0,0,0};
    f32x4 hA = {0,0,0,0}, hB = {0,0,0,0};
    int addrA = 0, addrB = 0;
    const bool selHi = (l & 32) != 0;

    if (wid == 0) {
        const f32x4* W4 = (const f32x4*)W_ih;
        split_frag(W4[c*8 + q*2], W4[c*8 + q*2 + 1], pA_h0, pA_l0);
        split_frag(W4[(c+16)*8 + q*2], W4[(c+16)*8 + q*2 + 1], pA_h1, pA_l1);
#pragma unroll
        for (int r = 0; r < 4; ++r) {
            bias0[r] = b_ih[q*4+r]    + b_hh[q*4+r];
            bias1[r] = b_ih[16+q*4+r] + b_hh[16+q*4+r];
        }
    } else {
        const f32x4* W4 = (const f32x4*)W_hh;
        split_frag(W4[c*8 + q*2], W4[c*8 + q*2 + 1], cA_h0, cA_l0);
        split_frag(W4[(c+16)*8 + q*2], W4[(c+16)*8 + q*2 + 1], cA_h1, cA_l1);
        const f32x4* H4 = (const f32x4*)(h0p + bglob*HD + q*8);
        split_frag(H4[0], H4[1], h_hi, h_lo);
#pragma unroll
        for (int r = 0; r < 4; ++r) {
            wo0[r] = W_out[q*4+r];
            wo1[r] = W_out[16+q*4+r];
        }
        // D->B rearrange: target quad q pulls from quads (2q)&3 and (2q+1)&3, same col.
        addrA = (((2*q)   & 3)*16 + c) << 2;
        addrB = (((2*q+1) & 3)*16 + c) << 2;
    }

    const f32x4* X4 = (const f32x4*)x;

    auto fill = [&](int bf, int ch) {
        f32x4 va[CH], vb[CH];
#pragma unroll
        for (int ti = 0; ti < CH; ++ti) {
            size_t off = ((size_t)bglob * T + (ch*CH + ti)) * (HD/4) + q*2;
            va[ti] = X4[off];
            vb[ti] = X4[off + 1];
        }
#pragma unroll
        for (int ti = 0; ti < CH; ++ti) {
            bf16x8 bx_h, bx_l;
            split_frag(va[ti], vb[ti], bx_h, bx_l);
            f32x4 p0 = bias0, p1 = bias1;
            p0 = MFMA(pA_h0, bx_h, p0);
            p1 = MFMA(pA_h1, bx_h, p1);
            p0 = MFMA(pA_h0, bx_l, p0);
            p1 = MFMA(pA_h1, bx_l, p1);
            p0 = MFMA(pA_l0, bx_h, p0);
            p1 = MFMA(pA_l1, bx_h, p1);
            xp_lds[bf][ti][0][l] = p0;
            xp_lds[bf][ti][1][l] = p1;
        }
    };

    auto consume = [&](int bf) {
#pragma unroll
        for (int ti = 0; ti < CH; ++ti) {
            f32x4 a0 = xp_lds[bf][ti][0][l];   // C-in = xp (bias already folded)
            f32x4 a1 = xp_lds[bf][ti][1][l];
            a0 = MFMA(cA_h0, h_hi, a0);
            a1 = MFMA(cA_h1, h_hi, a1);
            a0 = MFMA(cA_h0, h_lo, a0);
            a1 = MFMA(cA_h1, h_lo, a1);
            a0 = MFMA(cA_l0, h_hi, a0);
            a1 = MFMA(cA_l1, h_hi, a1);
#pragma unroll
            for (int r = 0; r < 4; ++r) {
                a0[r] = fmaxf(a0[r], 0.0f);
                a1[r] = fmaxf(a1[r], 0.0f);
            }
            // split to bf16 packed dwords: d = hi, e = lo residual
            int d00,e00,d01,e01,d10,e10,d11,e11;
            split_pair(a0[0], a0[1], d00, e00);
            split_pair(a0[2], a0[3], d01, e01);
            split_pair(a1[0], a1[1], d10, e10);
            split_pair(a1[2], a1[3], d11, e11);
            // D-layout -> B-layout: all bpermutes executed by all lanes, then select.
            int zA0h = BPERM(addrA, d00), zA1h = BPERM(addrA, d10);
            int yA0h = BPERM(addrA, d01), yA1h = BPERM(addrA, d11);
            int zB0h = BPERM(addrB, d00), zB1h = BPERM(addrB, d10);
            int yB0h = BPERM(addrB, d01), yB1h = BPERM(addrB, d11);
            int zA0l = BPERM(addrA, e00), zA1l = BPERM(addrA, e10);
            int yA0l = BPERM(addrA, e01), yA1l = BPERM(addrA, e11);
            int zB0l = BPERM(addrB, e00), zB1l = BPERM(addrB, e10);
            int yB0l = BPERM(addrB, e01), yB1l = BPERM(addrB, e11);
            int w0h = selHi ? zA1h : zA0h;
            int w1h = selHi ? yA1h : yA0h;
            int w2h = selHi ? zB1h : zB0h;
            int w3h = selHi ? yB1h : yB0h;
            int w0l = selHi ? zA1l : zA0l;
            int w1l = selHi ? yA1l : yA0l;
            int w2l = selHi ? zB1l : zB0l;
            int w3l = selHi ? yB1l : yB0l;
            h_hi = pack4(w0h, w1h, w2h, w3h);
            h_lo = pack4(w0l, w1l, w2l, w3l);
            hA = a0; hB = a1;
        }
    };

    if (wid == 0) fill(0, 0);
    __syncthreads();
    int buf = 0;
    for (int ch = 0; ch < nch; ++ch) {
        if (wid == 0) {
            if (ch + 1 < nch) fill(buf ^ 1, ch + 1);
        } else {
            consume(buf);
        }
        __syncthreads();
        buf ^= 1;
    }

    if (wid == 1) {
        // hT: out[B + b*32 + j], lane holds rows q*4+r (half0) / 16+q*4+r (half1) of col c
        float* outh = out + B + (size_t)bglob * HD;
#pragma unroll
        for (int r = 0; r < 4; ++r) {
            outh[q*4 + r]      = hA[r];
            outh[16 + q*4 + r] = hB[r];
        }
        // pred[b] = sum_j hT[b,j]*W_out[j] + b_out
        float p = 0.f;
#pragma unroll
        for (int r = 0; r < 4; ++r) p += hA[r]*wo0[r] + hB[r]*wo1[r];
        p += __int_as_float(BPERM((l ^ 16) << 2, __float_as_int(p)));
        p += __int_as_float(BPERM((l ^ 32) << 2, __float_as_int(p)));
        if (q == 0) out[bglob] = p + b_out[0];
    }
}

extern "C" void kernel_launch(void* const* d_in, const int* in_sizes, int n_in,
                              void* d_out, int out_size, void* d_ws, size_t ws_size,
                              hipStream_t stream) {
    const float* x      = (const float*)d_in[0];
    const float* hidden = (const float*)d_in[1];
    const float* W_ih   = (const float*)d_in[2];
    const float* W_hh   = (const float*)d_in[3];
    const float* b_ih   = (const float*)d_in[4];
    const float* b_hh   = (const float*)d_in[5];
    const float* W_out  = (const float*)d_in[6];
    const float* b_out  = (const float*)d_in[7];
    float* out = (float*)d_out;

    const int B = in_sizes[1] / HD;           // hidden is (1, B, H)
    const int T = in_sizes[0] / (B * HD);     // x is (B, T, 32)

    rnn_mfma<<<dim3(B / 16), dim3(128), 0, stream>>>(
        x, hidden, W_ih, W_hh, b_ih, b_hh, W_out, b_out, out, B, T);
}